// Round 8
// baseline (257.522 us; speedup 1.0000x reference)
//
#include <hip/hip_runtime.h>
#include <hip/hip_bf16.h>
#include <stdint.h>

#define DEV_INLINE __device__ __forceinline__

typedef __attribute__((ext_vector_type(4))) float f32x4;
typedef __attribute__((ext_vector_type(16))) float f32x16;
typedef __attribute__((ext_vector_type(8))) short short8;

static constexpr int S_LEN = 2048;
static constexpr int DM = 1024;
static constexpr int NH = 16;
static constexpr int DK = 64;
static constexpr int BATCH = 4;
static constexpr int M_TOT = BATCH * S_LEN;  // 8192

// Q pre-scale: (1/sqrt(64)) * log2(e) so softmax runs in exp2 domain.
#define QSCALE 0.18033688011112042f

DEV_INLINE unsigned short bf_round(float x) {
  unsigned u = __builtin_bit_cast(unsigned, x);
  u += 0x7fffu + ((u >> 16) & 1u);
  return (unsigned short)(u >> 16);
}

// ---------------- fp32 -> bf16 convert, all 5 tensors in one dispatch ----------------
struct CvtArgs {
  const float* in[5];
  unsigned short* out[5];
};
__global__ __launch_bounds__(256) void cvt_all(CvtArgs a) {
  int bid = blockIdx.x;
  int which, base;
  if (bid < 4096) { which = 0; base = bid; }
  else { int r = bid - 4096; which = 1 + (r >> 9); base = r & 511; }
  const float* __restrict__ in = a.in[which];
  unsigned short* __restrict__ out = a.out[which];
  long i = ((long)base * 256 + threadIdx.x) * 8;
  float4 va = *reinterpret_cast<const float4*>(in + i);
  float4 vb = *reinterpret_cast<const float4*>(in + i + 4);
  union { unsigned short u[8]; uint4 v; } pk;
  pk.u[0] = bf_round(va.x); pk.u[1] = bf_round(va.y);
  pk.u[2] = bf_round(va.z); pk.u[3] = bf_round(va.w);
  pk.u[4] = bf_round(vb.x); pk.u[5] = bf_round(vb.y);
  pk.u[6] = bf_round(vb.z); pk.u[7] = bf_round(vb.w);
  *reinterpret_cast<uint4*>(out + i) = pk.v;
}

// ---------------- async global->LDS 16B ----------------
DEV_INLINE void gload_lds16(const unsigned short* g, unsigned short* l) {
  __builtin_amdgcn_global_load_lds(
      (const __attribute__((address_space(1))) unsigned int*)g,
      (__attribute__((address_space(3))) unsigned int*)l,
      16, 0, 0);
}

// ---------------- fused QKV GEMM ----------------
struct QkvArgs {
  const unsigned short* W[3];
  const float* bias[3];
  unsigned short* out[3];
};
__global__ __launch_bounds__(256) void gemm_qkv(const unsigned short* __restrict__ A,
                                                QkvArgs args) {
  constexpr int K = DM;
  __shared__ unsigned short lA[128 * 32];
  __shared__ unsigned short lB[128 * 32];
  const int tid = threadIdx.x;
  const int wave = tid >> 6, lane = tid & 63;
  const int wm = wave >> 1, wn = wave & 1;
  const int g = lane >> 4, c = lane & 15;
  const int bm = blockIdx.x, bn = blockIdx.y, z = blockIdx.z;

  const unsigned short* __restrict__ W = args.W[z];
  const float* __restrict__ bias = args.bias[z];
  unsigned short* __restrict__ outp = args.out[z];

  const int srow = lane >> 2;
  const int scol = (lane & 3) * 8;

  f32x4 acc[4][4] = {};

  const unsigned short* Abase = A + (long)(bm * 128) * K;
  const unsigned short* Wbase = W + (long)(bn * 128) * K;

  for (int k0 = 0; k0 < K; k0 += 32) {
    __syncthreads();
#pragma unroll
    for (int i = 0; i < 2; ++i) {
      const int row = i * 64 + wave * 16;
      gload_lds16(Abase + (long)(row + srow) * K + k0 + scol, lA + row * 32);
      gload_lds16(Wbase + (long)(row + srow) * K + k0 + scol, lB + row * 32);
    }
    __syncthreads();

    short8 af[4], bf[4];
#pragma unroll
    for (int mi = 0; mi < 4; ++mi)
      af[mi] = *reinterpret_cast<const short8*>(&lA[(wm * 64 + mi * 16 + c) * 32 + g * 8]);
#pragma unroll
    for (int ni = 0; ni < 4; ++ni)
      bf[ni] = *reinterpret_cast<const short8*>(&lB[(wn * 64 + ni * 16 + c) * 32 + g * 8]);
#pragma unroll
    for (int mi = 0; mi < 4; ++mi)
#pragma unroll
      for (int ni = 0; ni < 4; ++ni)
        acc[mi][ni] =
            __builtin_amdgcn_mfma_f32_16x16x32_bf16(af[mi], bf[ni], acc[mi][ni], 0, 0, 0);
  }

#pragma unroll
  for (int mi = 0; mi < 4; ++mi) {
#pragma unroll
    for (int ni = 0; ni < 4; ++ni) {
      const int mg0 = bm * 128 + wm * 64 + mi * 16 + g * 4;
      const int ng = bn * 128 + wn * 64 + ni * 16 + c;
      const float bv = bias[ng];
#pragma unroll
      for (int r = 0; r < 4; ++r) {
        const int m = mg0 + r;
        float v = acc[mi][ni][r] + bv;
        if (z == 0) v *= QSCALE;
        const int b_ = m >> 11, s_ = m & 2047, h_ = ng >> 6, d_ = ng & 63;
        if (z < 2) {
          outp[((long)(b_ * NH + h_) * S_LEN + s_) * DK + d_] = bf_round(v);
        } else {
          outp[((long)(b_ * NH + h_) * DK + d_) * S_LEN + s_] = bf_round(v);
        }
      }
    }
  }
}

// ---------------- output-projection GEMM (fp32 out) ----------------
__global__ __launch_bounds__(256) void gemm_out(const unsigned short* __restrict__ A,
                                                const unsigned short* __restrict__ W,
                                                const float* __restrict__ bias,
                                                float* __restrict__ outp) {
  constexpr int K = DM, N = DM;
  __shared__ unsigned short lA[128 * 32];
  __shared__ unsigned short lB[128 * 32];
  const int tid = threadIdx.x;
  const int wave = tid >> 6, lane = tid & 63;
  const int wm = wave >> 1, wn = wave & 1;
  const int g = lane >> 4, c = lane & 15;
  const int bm = blockIdx.x, bn = blockIdx.y;

  const int srow = lane >> 2;
  const int scol = (lane & 3) * 8;

  f32x4 acc[4][4] = {};

  const unsigned short* Abase = A + (long)(bm * 128) * K;
  const unsigned short* Wbase = W + (long)(bn * 128) * K;

  for (int k0 = 0; k0 < K; k0 += 32) {
    __syncthreads();
#pragma unroll
    for (int i = 0; i < 2; ++i) {
      const int row = i * 64 + wave * 16;
      gload_lds16(Abase + (long)(row + srow) * K + k0 + scol, lA + row * 32);
      gload_lds16(Wbase + (long)(row + srow) * K + k0 + scol, lB + row * 32);
    }
    __syncthreads();

    short8 af[4], bf[4];
#pragma unroll
    for (int mi = 0; mi < 4; ++mi)
      af[mi] = *reinterpret_cast<const short8*>(&lA[(wm * 64 + mi * 16 + c) * 32 + g * 8]);
#pragma unroll
    for (int ni = 0; ni < 4; ++ni)
      bf[ni] = *reinterpret_cast<const short8*>(&lB[(wn * 64 + ni * 16 + c) * 32 + g * 8]);
#pragma unroll
    for (int mi = 0; mi < 4; ++mi)
#pragma unroll
      for (int ni = 0; ni < 4; ++ni)
        acc[mi][ni] =
            __builtin_amdgcn_mfma_f32_16x16x32_bf16(af[mi], bf[ni], acc[mi][ni], 0, 0, 0);
  }

#pragma unroll
  for (int mi = 0; mi < 4; ++mi) {
#pragma unroll
    for (int ni = 0; ni < 4; ++ni) {
      const int mg0 = bm * 128 + wm * 64 + mi * 16 + g * 4;
      const int ng = bn * 128 + wn * 64 + ni * 16 + c;
      const float bv = bias[ng];
#pragma unroll
      for (int r = 0; r < 4; ++r)
        outp[(long)(mg0 + r) * N + ng] = acc[mi][ni][r] + bv;
    }
  }
}

// ---------------- Flash attention: 2-phase LDS-staged, KV tile 64, 64 q/wave ----------------
// Q: [BH][S][DK] bf16 (pre-scaled QSCALE), K: [BH][S][DK] bf16, Vt: [BH][DK][S] bf16
// ctx out: [B][S][H*DK] bf16.
// Block = 4 waves x 64 q-rows (256 q/block), grid 512, full KV sweep (32 iters).
// Round-8: TWO q-tiles per wave sharing one kf/vf read -> LDS reads per FLOP halve
// (the round-7 profile showed LDS port ~46% busy from 4x tile read amplification);
// two independent softmax chains interleave in one straight-line block.
__global__ __launch_bounds__(256) void attn_kernel(const unsigned short* __restrict__ Q,
                                                   const unsigned short* __restrict__ Kb,
                                                   const unsigned short* __restrict__ Vt,
                                                   unsigned short* __restrict__ ctx) {
  __shared__ unsigned short kbuf[2][64 * 64];  // [kv row][d], 128B rows, swizzled
  __shared__ unsigned short vbuf[2][64 * 64];  // [d row][kv], 128B rows, swizzled
  const int tid = threadIdx.x, wave = tid >> 6, lane = tid & 63;
  const int q = lane & 31;   // q column; also K/V LDS row selector
  const int h = lane >> 5;   // half-wave: owns k-slice h*8..h*8+7 of frags
  const int bid = blockIdx.x;
  const int swz = (bid & 7) * 64 + (bid >> 3);  // nwg=512, 8 XCDs, bijective
  const int hd = swz >> 3, qb = swz & 7;
  const int q0 = qb * 256 + wave * 64;          // wave owns q0..q0+63

  const unsigned short* Qh = Q + (long)hd * S_LEN * DK;
  const char* KhB = (const char*)(Kb + (long)hd * S_LEN * DK);
  const char* VhB = (const char*)(Vt + (long)hd * DK * S_LEN);

  // staging geometry: each gload covers 8 rows x 128B; source col pre-swizzled
  const int srow_in = lane >> 3;                           // 0..7
  const int scolb = ((lane & 7) * 16) ^ (srow_in << 4);    // swizzled source byte col

  // swizzled LDS read: 16B at (row, colbyte)
  auto ldsrd = [&](const unsigned short* buf, int row, int colbyte) -> short8 {
    return *reinterpret_cast<const short8*>(
        reinterpret_cast<const char*>(buf) + row * 128 + (colbyte ^ ((row & 7) << 4)));
  };

  auto stage = [&](int b, int kv0) {
#pragma unroll
    for (int r = 0; r < 2; ++r) {
      const int rowbase = (wave * 2 + r) * 8;          // wave-uniform
      const int row = rowbase + srow_in;
      gload_lds16((const unsigned short*)(KhB + (long)(kv0 + row) * 128 + scolb),
                  &kbuf[b][rowbase * 64]);
      gload_lds16((const unsigned short*)(VhB + (long)row * (S_LEN * 2) + kv0 * 2 + scolb),
                  &vbuf[b][rowbase * 64]);
    }
  };

  short8 qf0[4], qf1[4];  // q-tile 0: rows q0+q; q-tile 1: rows q0+32+q
#pragma unroll
  for (int d0 = 0; d0 < 4; ++d0) {
    qf0[d0] = *reinterpret_cast<const short8*>(&Qh[(long)(q0 + q) * DK + d0 * 16 + h * 8]);
    qf1[d0] = *reinterpret_cast<const short8*>(&Qh[(long)(q0 + 32 + q) * DK + d0 * 16 + h * 8]);
  }

  f32x16 c00 = {}, c01 = {};  // tile0 ctx^T: d 0-31, d 32-63
  f32x16 c10 = {}, c11 = {};  // tile1
  float m0 = -1e30f, l0 = 0.0f, m1 = -1e30f, l1 = 0.0f;  // per lane-half partials

  stage(0, 0);
  __syncthreads();

  int cur = 0;
  for (int t = 0; t < S_LEN / 64; ++t) {
    if (t + 1 < S_LEN / 64) stage(cur ^ 1, (t + 1) * 64);  // issue-early prefetch

    const unsigned short* kb = kbuf[cur];
    const unsigned short* vb = vbuf[cur];

    // ---- K frags read ONCE, feed both q-tiles ----
    short8 kfA[4], kfB[4];
#pragma unroll
    for (int d0 = 0; d0 < 4; ++d0) {
      kfA[d0] = ldsrd(kb, q, d0 * 32 + h * 16);
      kfB[d0] = ldsrd(kb, 32 + q, d0 * 32 + h * 16);
    }
    __builtin_amdgcn_s_setprio(1);
    f32x16 sA0 = {}, sB0 = {}, sA1 = {}, sB1 = {};
#pragma unroll
    for (int d0 = 0; d0 < 4; ++d0) {
      sA0 = __builtin_amdgcn_mfma_f32_32x32x16_bf16(kfA[d0], qf0[d0], sA0, 0, 0, 0);
      sB0 = __builtin_amdgcn_mfma_f32_32x32x16_bf16(kfB[d0], qf0[d0], sB0, 0, 0, 0);
      sA1 = __builtin_amdgcn_mfma_f32_32x32x16_bf16(kfA[d0], qf1[d0], sA1, 0, 0, 0);
      sB1 = __builtin_amdgcn_mfma_f32_32x32x16_bf16(kfB[d0], qf1[d0], sB1, 0, 0, 0);
    }
    __builtin_amdgcn_s_setprio(0);
    // lane reg r: q col = q, kv_local = (r&3) + 8*(r>>2) + 4*h  (+32 for B tiles)

    // ---- per-tile max trees (independent chains; interleaved by scheduler) ----
    float t0[16], t1[16];
#pragma unroll
    for (int r = 0; r < 16; ++r) { t0[r] = fmaxf(sA0[r], sB0[r]); t1[r] = fmaxf(sA1[r], sB1[r]); }
#pragma unroll
    for (int r = 0; r < 8; ++r) { t0[r] = fmaxf(t0[r], t0[r + 8]); t1[r] = fmaxf(t1[r], t1[r + 8]); }
#pragma unroll
    for (int r = 0; r < 4; ++r) { t0[r] = fmaxf(t0[r], t0[r + 4]); t1[r] = fmaxf(t1[r], t1[r + 4]); }
    const float pml0 = fmaxf(fmaxf(t0[0], t0[1]), fmaxf(t0[2], t0[3]));
    const float pml1 = fmaxf(fmaxf(t1[0], t1[1]), fmaxf(t1[2], t1[3]));

    if (__any(fmaxf(pml0 - m0, pml1 - m1) > 8.0f)) {  // rare shared rescale branch
      const float pm0 = fmaxf(pml0, __shfl_xor(pml0, 32));
      const float pm1 = fmaxf(pml1, __shfl_xor(pml1, 32));
      const float mn0 = fmaxf(m0, pm0), mn1 = fmaxf(m1, pm1);
      const float a0 = __builtin_amdgcn_exp2f(m0 - mn0);
      const float a1 = __builtin_amdgcn_exp2f(m1 - mn1);
      c00 *= a0; c01 *= a0; l0 *= a0; m0 = mn0;
      c10 *= a1; c11 *= a1; l1 *= a1; m1 = mn1;
    }

    // ---- exp + row-sum + pack, both tiles in one straight-line block ----
#pragma unroll
    for (int r = 0; r < 16; ++r) {
      sA0[r] = __builtin_amdgcn_exp2f(sA0[r] - m0);
      sB0[r] = __builtin_amdgcn_exp2f(sB0[r] - m0);
      sA1[r] = __builtin_amdgcn_exp2f(sA1[r] - m1);
      sB1[r] = __builtin_amdgcn_exp2f(sB1[r] - m1);
    }
    float u0[16], u1[16];
#pragma unroll
    for (int r = 0; r < 16; ++r) { u0[r] = sA0[r] + sB0[r]; u1[r] = sA1[r] + sB1[r]; }
#pragma unroll
    for (int r = 0; r < 8; ++r) { u0[r] += u0[r + 8]; u1[r] += u1[r + 8]; }
#pragma unroll
    for (int r = 0; r < 4; ++r) { u0[r] += u0[r + 4]; u1[r] += u1[r + 4]; }
    l0 += (u0[0] + u0[1]) + (u0[2] + u0[3]);
    l1 += (u1[0] + u1[1]) + (u1[2] + u1[3]);

    unsigned p0AA[4], p0AB[4], p0BA[4], p0BB[4];
    unsigned p1AA[4], p1AB[4], p1BA[4], p1BB[4];
#pragma unroll
    for (int rq = 0; rq < 4; ++rq) {
      asm("v_cvt_pk_bf16_f32 %0, %1, %2" : "=v"(p0AA[rq]) : "v"(sA0[4 * rq]), "v"(sA0[4 * rq + 1]));
      asm("v_cvt_pk_bf16_f32 %0, %1, %2" : "=v"(p0AB[rq]) : "v"(sA0[4 * rq + 2]), "v"(sA0[4 * rq + 3]));
      asm("v_cvt_pk_bf16_f32 %0, %1, %2" : "=v"(p0BA[rq]) : "v"(sB0[4 * rq]), "v"(sB0[4 * rq + 1]));
      asm("v_cvt_pk_bf16_f32 %0, %1, %2" : "=v"(p0BB[rq]) : "v"(sB0[4 * rq + 2]), "v"(sB0[4 * rq + 3]));
      asm("v_cvt_pk_bf16_f32 %0, %1, %2" : "=v"(p1AA[rq]) : "v"(sA1[4 * rq]), "v"(sA1[4 * rq + 1]));
      asm("v_cvt_pk_bf16_f32 %0, %1, %2" : "=v"(p1AB[rq]) : "v"(sA1[4 * rq + 2]), "v"(sA1[4 * rq + 3]));
      asm("v_cvt_pk_bf16_f32 %0, %1, %2" : "=v"(p1BA[rq]) : "v"(sB1[4 * rq]), "v"(sB1[4 * rq + 1]));
      asm("v_cvt_pk_bf16_f32 %0, %1, %2" : "=v"(p1BB[rq]) : "v"(sB1[4 * rq + 2]), "v"(sB1[4 * rq + 3]));
    }

    // ---- PV: V frags read ONCE, feed both q-tiles ----
    unsigned r0A[4], r0B[4], r1A[4], r1B[4];
#pragma unroll
    for (int s = 0; s < 4; ++s) {
      const unsigned a00 = (s < 2 ? p0AA : p0BA)[2 * (s & 1)];
      const unsigned a01 = (s < 2 ? p0AA : p0BA)[2 * (s & 1) + 1];
      const unsigned b00 = (s < 2 ? p0AB : p0BB)[2 * (s & 1)];
      const unsigned b01 = (s < 2 ? p0AB : p0BB)[2 * (s & 1) + 1];
      r0A[s] = (unsigned)__shfl_xor((int)(h ? a00 : a01), 32);
      r0B[s] = (unsigned)__shfl_xor((int)(h ? b00 : b01), 32);
      const unsigned a10 = (s < 2 ? p1AA : p1BA)[2 * (s & 1)];
      const unsigned a11 = (s < 2 ? p1AA : p1BA)[2 * (s & 1) + 1];
      const unsigned b10 = (s < 2 ? p1AB : p1BB)[2 * (s & 1)];
      const unsigned b11 = (s < 2 ? p1AB : p1BB)[2 * (s & 1) + 1];
      r1A[s] = (unsigned)__shfl_xor((int)(h ? a10 : a11), 32);
      r1B[s] = (unsigned)__shfl_xor((int)(h ? b10 : b11), 32);
    }
    short8 vf0[4], vf1[4];
#pragma unroll
    for (int s = 0; s < 4; ++s) {
      vf0[s] = ldsrd(vb, q, s * 32 + h * 16);
      vf1[s] = ldsrd(vb, 32 + q, s * 32 + h * 16);
    }
    __builtin_amdgcn_s_setprio(1);
#pragma unroll
    for (int s = 0; s < 4; ++s) {
      const unsigned a00 = (s < 2 ? p0AA : p0BA)[2 * (s & 1)];
      const unsigned a01 = (s < 2 ? p0AA : p0BA)[2 * (s & 1) + 1];
      const unsigned b00 = (s < 2 ? p0AB : p0BB)[2 * (s & 1)];
      const unsigned b01 = (s < 2 ? p0AB : p0BB)[2 * (s & 1) + 1];
      union { unsigned w[4]; short8 v; } pf0;
      pf0.w[0] = h ? r0A[s] : a00;
      pf0.w[1] = h ? r0B[s] : b00;
      pf0.w[2] = h ? a01 : r0A[s];
      pf0.w[3] = h ? b01 : r0B[s];
      c00 = __builtin_amdgcn_mfma_f32_32x32x16_bf16(vf0[s], pf0.v, c00, 0, 0, 0);
      c01 = __builtin_amdgcn_mfma_f32_32x32x16_bf16(vf1[s], pf0.v, c01, 0, 0, 0);
      const unsigned a10 = (s < 2 ? p1AA : p1BA)[2 * (s & 1)];
      const unsigned a11 = (s < 2 ? p1AA : p1BA)[2 * (s & 1) + 1];
      const unsigned b10 = (s < 2 ? p1AB : p1BB)[2 * (s & 1)];
      const unsigned b11 = (s < 2 ? p1AB : p1BB)[2 * (s & 1) + 1];
      union { unsigned w[4]; short8 v; } pf1;
      pf1.w[0] = h ? r1A[s] : a10;
      pf1.w[1] = h ? r1B[s] : b10;
      pf1.w[2] = h ? a11 : r1A[s];
      pf1.w[3] = h ? b11 : r1B[s];
      c10 = __builtin_amdgcn_mfma_f32_32x32x16_bf16(vf0[s], pf1.v, c10, 0, 0, 0);
      c11 = __builtin_amdgcn_mfma_f32_32x32x16_bf16(vf1[s], pf1.v, c11, 0, 0, 0);
    }
    __builtin_amdgcn_s_setprio(0);

    __syncthreads();  // drains stage loads; protects both buffers
    cur ^= 1;
  }

  // ---- combine lane-half l-sums, then epilogue for both q-tiles ----
  l0 += __shfl_xor(l0, 32);
  l1 += __shfl_xor(l1, 32);
  const float inv0 = 1.0f / l0, inv1 = 1.0f / l1;
  const int b_ = hd >> 4, h_ = hd & 15;
  const long row0 = ((long)b_ * S_LEN + q0 + q) * DM + h_ * DK;
  const long row1 = ((long)b_ * S_LEN + q0 + 32 + q) * DM + h_ * DK;
#pragma unroll
  for (int rq = 0; rq < 4; ++rq) {
    ushort4 w0, w1, w2, w3;
    w0.x = bf_round(c00[4 * rq + 0] * inv0);
    w0.y = bf_round(c00[4 * rq + 1] * inv0);
    w0.z = bf_round(c00[4 * rq + 2] * inv0);
    w0.w = bf_round(c00[4 * rq + 3] * inv0);
    w1.x = bf_round(c01[4 * rq + 0] * inv0);
    w1.y = bf_round(c01[4 * rq + 1] * inv0);
    w1.z = bf_round(c01[4 * rq + 2] * inv0);
    w1.w = bf_round(c01[4 * rq + 3] * inv0);
    w2.x = bf_round(c10[4 * rq + 0] * inv1);
    w2.y = bf_round(c10[4 * rq + 1] * inv1);
    w2.z = bf_round(c10[4 * rq + 2] * inv1);
    w2.w = bf_round(c10[4 * rq + 3] * inv1);
    w3.x = bf_round(c11[4 * rq + 0] * inv1);
    w3.y = bf_round(c11[4 * rq + 1] * inv1);
    w3.z = bf_round(c11[4 * rq + 2] * inv1);
    w3.w = bf_round(c11[4 * rq + 3] * inv1);
    *reinterpret_cast<ushort4*>(&ctx[row0 + 8 * rq + 4 * h]) = w0;
    *reinterpret_cast<ushort4*>(&ctx[row0 + 32 + 8 * rq + 4 * h]) = w1;
    *reinterpret_cast<ushort4*>(&ctx[row1 + 8 * rq + 4 * h]) = w2;
    *reinterpret_cast<ushort4*>(&ctx[row1 + 32 + 8 * rq + 4 * h]) = w3;
  }
}

extern "C" void kernel_launch(void* const* d_in, const int* in_sizes, int n_in,
                              void* d_out, int out_size, void* d_ws, size_t ws_size,
                              hipStream_t stream) {
  const float* X  = (const float*)d_in[0];
  const float* Wq = (const float*)d_in[1];
  const float* bq = (const float*)d_in[2];
  const float* Wk = (const float*)d_in[3];
  const float* bk = (const float*)d_in[4];
  const float* Wv = (const float*)d_in[5];
  const float* bv = (const float*)d_in[6];
  const float* Wo = (const float*)d_in[7];
  const float* bo = (const float*)d_in[8];

  char* ws = (char*)d_ws;
  const long MB = 1l << 20;
  unsigned short* Xbf = (unsigned short*)(ws + 0 * MB);   // 16 MB
  unsigned short* Ctx = Xbf;                              // alias: X dead after V GEMM
  unsigned short* Wqb = (unsigned short*)(ws + 16 * MB);  // 2 MB each
  unsigned short* Wkb = (unsigned short*)(ws + 18 * MB);
  unsigned short* Wvb = (unsigned short*)(ws + 20 * MB);
  unsigned short* Wob = (unsigned short*)(ws + 22 * MB);
  unsigned short* Qb  = (unsigned short*)(ws + 24 * MB);  // 16 MB
  unsigned short* Kbf = (unsigned short*)(ws + 40 * MB);  // 16 MB
  unsigned short* Vtb = (unsigned short*)(ws + 56 * MB);  // 16 MB, ends at 72 MB

  CvtArgs ca;
  ca.in[0] = X;  ca.out[0] = Xbf;
  ca.in[1] = Wq; ca.out[1] = Wqb;
  ca.in[2] = Wk; ca.out[2] = Wkb;
  ca.in[3] = Wv; ca.out[3] = Wvb;
  ca.in[4] = Wo; ca.out[4] = Wob;
  cvt_all<<<4096 + 4 * 512, 256, 0, stream>>>(ca);

  QkvArgs qa;
  qa.W[0] = Wqb; qa.bias[0] = bq; qa.out[0] = Qb;
  qa.W[1] = Wkb; qa.bias[1] = bk; qa.out[1] = Kbf;
  qa.W[2] = Wvb; qa.bias[2] = bv; qa.out[2] = Vtb;
  gemm_qkv<<<dim3(M_TOT / 128, DM / 128, 3), 256, 0, stream>>>(Xbf, qa);

  attn_kernel<<<dim3(512), 256, 0, stream>>>(Qb, Kbf, Vtb, Ctx);

  gemm_out<<<dim3(M_TOT / 128, DM / 128), 256, 0, stream>>>(Ctx, Wob, bo, (float*)d_out);
}

// Round 10
// 226.541 us; speedup vs baseline: 1.1368x; 1.1368x over previous
//
#include <hip/hip_runtime.h>
#include <hip/hip_bf16.h>
#include <stdint.h>

#define DEV_INLINE __device__ __forceinline__

typedef __attribute__((ext_vector_type(4))) float f32x4;
typedef __attribute__((ext_vector_type(16))) float f32x16;
typedef __attribute__((ext_vector_type(8))) short short8;

static constexpr int S_LEN = 2048;
static constexpr int DM = 1024;
static constexpr int NH = 16;
static constexpr int DK = 64;
static constexpr int BATCH = 4;
static constexpr int M_TOT = BATCH * S_LEN;  // 8192

// Q pre-scale: (1/sqrt(64)) * log2(e) so softmax runs in exp2 domain.
#define QSCALE 0.18033688011112042f

DEV_INLINE unsigned short bf_round(float x) {
  unsigned u = __builtin_bit_cast(unsigned, x);
  u += 0x7fffu + ((u >> 16) & 1u);
  return (unsigned short)(u >> 16);
}

// ---------------- fp32 -> bf16 convert, all 5 tensors in one dispatch ----------------
struct CvtArgs {
  const float* in[5];
  unsigned short* out[5];
};
__global__ __launch_bounds__(256) void cvt_all(CvtArgs a) {
  int bid = blockIdx.x;
  int which, base;
  if (bid < 4096) { which = 0; base = bid; }
  else { int r = bid - 4096; which = 1 + (r >> 9); base = r & 511; }
  const float* __restrict__ in = a.in[which];
  unsigned short* __restrict__ out = a.out[which];
  long i = ((long)base * 256 + threadIdx.x) * 8;
  float4 va = *reinterpret_cast<const float4*>(in + i);
  float4 vb = *reinterpret_cast<const float4*>(in + i + 4);
  union { unsigned short u[8]; uint4 v; } pk;
  pk.u[0] = bf_round(va.x); pk.u[1] = bf_round(va.y);
  pk.u[2] = bf_round(va.z); pk.u[3] = bf_round(va.w);
  pk.u[4] = bf_round(vb.x); pk.u[5] = bf_round(vb.y);
  pk.u[6] = bf_round(vb.z); pk.u[7] = bf_round(vb.w);
  *reinterpret_cast<uint4*>(out + i) = pk.v;
}

// ---------------- async global->LDS 16B ----------------
DEV_INLINE void gload_lds16(const unsigned short* g, unsigned short* l) {
  __builtin_amdgcn_global_load_lds(
      (const __attribute__((address_space(1))) unsigned int*)g,
      (__attribute__((address_space(3))) unsigned int*)l,
      16, 0, 0);
}

// ---------------- fused QKV GEMM ----------------
struct QkvArgs {
  const unsigned short* W[3];
  const float* bias[3];
  unsigned short* out[3];
};
__global__ __launch_bounds__(256) void gemm_qkv(const unsigned short* __restrict__ A,
                                                QkvArgs args) {
  constexpr int K = DM;
  __shared__ unsigned short lA[128 * 32];
  __shared__ unsigned short lB[128 * 32];
  const int tid = threadIdx.x;
  const int wave = tid >> 6, lane = tid & 63;
  const int wm = wave >> 1, wn = wave & 1;
  const int g = lane >> 4, c = lane & 15;
  const int bm = blockIdx.x, bn = blockIdx.y, z = blockIdx.z;

  const unsigned short* __restrict__ W = args.W[z];
  const float* __restrict__ bias = args.bias[z];
  unsigned short* __restrict__ outp = args.out[z];

  const int srow = lane >> 2;
  const int scol = (lane & 3) * 8;

  f32x4 acc[4][4] = {};

  const unsigned short* Abase = A + (long)(bm * 128) * K;
  const unsigned short* Wbase = W + (long)(bn * 128) * K;

  for (int k0 = 0; k0 < K; k0 += 32) {
    __syncthreads();
#pragma unroll
    for (int i = 0; i < 2; ++i) {
      const int row = i * 64 + wave * 16;
      gload_lds16(Abase + (long)(row + srow) * K + k0 + scol, lA + row * 32);
      gload_lds16(Wbase + (long)(row + srow) * K + k0 + scol, lB + row * 32);
    }
    __syncthreads();

    short8 af[4], bf[4];
#pragma unroll
    for (int mi = 0; mi < 4; ++mi)
      af[mi] = *reinterpret_cast<const short8*>(&lA[(wm * 64 + mi * 16 + c) * 32 + g * 8]);
#pragma unroll
    for (int ni = 0; ni < 4; ++ni)
      bf[ni] = *reinterpret_cast<const short8*>(&lB[(wn * 64 + ni * 16 + c) * 32 + g * 8]);
#pragma unroll
    for (int mi = 0; mi < 4; ++mi)
#pragma unroll
      for (int ni = 0; ni < 4; ++ni)
        acc[mi][ni] =
            __builtin_amdgcn_mfma_f32_16x16x32_bf16(af[mi], bf[ni], acc[mi][ni], 0, 0, 0);
  }

#pragma unroll
  for (int mi = 0; mi < 4; ++mi) {
#pragma unroll
    for (int ni = 0; ni < 4; ++ni) {
      const int mg0 = bm * 128 + wm * 64 + mi * 16 + g * 4;
      const int ng = bn * 128 + wn * 64 + ni * 16 + c;
      const float bv = bias[ng];
#pragma unroll
      for (int r = 0; r < 4; ++r) {
        const int m = mg0 + r;
        float v = acc[mi][ni][r] + bv;
        if (z == 0) v *= QSCALE;
        const int b_ = m >> 11, s_ = m & 2047, h_ = ng >> 6, d_ = ng & 63;
        if (z < 2) {
          outp[((long)(b_ * NH + h_) * S_LEN + s_) * DK + d_] = bf_round(v);
        } else {
          outp[((long)(b_ * NH + h_) * DK + d_) * S_LEN + s_] = bf_round(v);
        }
      }
    }
  }
}

// ---------------- output-projection GEMM (fp32 out) ----------------
__global__ __launch_bounds__(256) void gemm_out(const unsigned short* __restrict__ A,
                                                const unsigned short* __restrict__ W,
                                                const float* __restrict__ bias,
                                                float* __restrict__ outp) {
  constexpr int K = DM, N = DM;
  __shared__ unsigned short lA[128 * 32];
  __shared__ unsigned short lB[128 * 32];
  const int tid = threadIdx.x;
  const int wave = tid >> 6, lane = tid & 63;
  const int wm = wave >> 1, wn = wave & 1;
  const int g = lane >> 4, c = lane & 15;
  const int bm = blockIdx.x, bn = blockIdx.y;

  const int srow = lane >> 2;
  const int scol = (lane & 3) * 8;

  f32x4 acc[4][4] = {};

  const unsigned short* Abase = A + (long)(bm * 128) * K;
  const unsigned short* Wbase = W + (long)(bn * 128) * K;

  for (int k0 = 0; k0 < K; k0 += 32) {
    __syncthreads();
#pragma unroll
    for (int i = 0; i < 2; ++i) {
      const int row = i * 64 + wave * 16;
      gload_lds16(Abase + (long)(row + srow) * K + k0 + scol, lA + row * 32);
      gload_lds16(Wbase + (long)(row + srow) * K + k0 + scol, lB + row * 32);
    }
    __syncthreads();

    short8 af[4], bf[4];
#pragma unroll
    for (int mi = 0; mi < 4; ++mi)
      af[mi] = *reinterpret_cast<const short8*>(&lA[(wm * 64 + mi * 16 + c) * 32 + g * 8]);
#pragma unroll
    for (int ni = 0; ni < 4; ++ni)
      bf[ni] = *reinterpret_cast<const short8*>(&lB[(wn * 64 + ni * 16 + c) * 32 + g * 8]);
#pragma unroll
    for (int mi = 0; mi < 4; ++mi)
#pragma unroll
      for (int ni = 0; ni < 4; ++ni)
        acc[mi][ni] =
            __builtin_amdgcn_mfma_f32_16x16x32_bf16(af[mi], bf[ni], acc[mi][ni], 0, 0, 0);
  }

#pragma unroll
  for (int mi = 0; mi < 4; ++mi) {
#pragma unroll
    for (int ni = 0; ni < 4; ++ni) {
      const int mg0 = bm * 128 + wm * 64 + mi * 16 + g * 4;
      const int ng = bn * 128 + wn * 64 + ni * 16 + c;
      const float bv = bias[ng];
#pragma unroll
      for (int r = 0; r < 4; ++r)
        outp[(long)(mg0 + r) * N + ng] = acc[mi][ni][r] + bv;
    }
  }
}

// ---------------- Flash attention: LDS-staged, KV tile 128 (2x64 sub-tiles) ----------------
// Q: [BH][S][DK] bf16 (pre-scaled QSCALE), K: [BH][S][DK] bf16, Vt: [BH][DK][S] bf16
// ctx out: [B][S][H*DK] bf16.
// Block = 4 waves x 32 q-rows (R7 proven numerics: defer-max + pair-uniform m).
// Round-10: (a) REVERT no-max (R9 failed 2.1e-2); (b) 128-kv stage per barrier pair
// as two proven 64-kv sub-buffers -> halves __syncthreads+vmcnt drains (32->16);
// (c) l-sum via ones-MFMA on the matrix pipe (consistent numerator/denominator:
// out = sum(p̂ v̂)/sum(p̂) is a true weighted mean -> error bounded), replacing the
// 31-op VALU sum tree + end shfl. lacc rescales by alpha in the rare branch.
__global__ __launch_bounds__(256) void attn_kernel(const unsigned short* __restrict__ Q,
                                                   const unsigned short* __restrict__ Kb,
                                                   const unsigned short* __restrict__ Vt,
                                                   unsigned short* __restrict__ ctx) {
  __shared__ unsigned short kbuf[2][2][64 * 64];  // [buf][sub][kv row][d], swizzled
  __shared__ unsigned short vbuf[2][2][64 * 64];  // [buf][sub][d row][kv], swizzled
  const int tid = threadIdx.x, wave = tid >> 6, lane = tid & 63;
  const int q = lane & 31;   // q column; also K/V LDS row selector
  const int h = lane >> 5;   // half-wave: owns k-slice h*8..h*8+7 of frags
  const int bid = blockIdx.x;
  const int swz = (bid & 7) * 128 + (bid >> 3);  // nwg=1024, 8 XCDs, bijective
  const int hd = swz >> 4, qb = swz & 15;
  const int q0 = qb * 128 + wave * 32;

  const unsigned short* Qh = Q + (long)hd * S_LEN * DK;
  const char* KhB = (const char*)(Kb + (long)hd * S_LEN * DK);
  const char* VhB = (const char*)(Vt + (long)hd * DK * S_LEN);

  // staging geometry: each gload covers 8 rows x 128B; source col pre-swizzled
  const int srow_in = lane >> 3;                           // 0..7
  const int scolb = ((lane & 7) * 16) ^ (srow_in << 4);    // swizzled source byte col

  // swizzled LDS read: 16B at (row, colbyte)
  auto ldsrd = [&](const unsigned short* buf, int row, int colbyte) -> short8 {
    return *reinterpret_cast<const short8*>(
        reinterpret_cast<const char*>(buf) + row * 128 + (colbyte ^ ((row & 7) << 4)));
  };

  // stage a 128-kv tile (two 64-kv sub-buffers), 8 gloads per wave
  auto stage = [&](int b, int kv0) {
#pragma unroll
    for (int sub = 0; sub < 2; ++sub) {
#pragma unroll
      for (int r = 0; r < 2; ++r) {
        const int rowbase = (wave * 2 + r) * 8;          // wave-uniform
        const int row = rowbase + srow_in;
        gload_lds16((const unsigned short*)(KhB + (long)(kv0 + sub * 64 + row) * 128 + scolb),
                    &kbuf[b][sub][rowbase * 64]);
        gload_lds16((const unsigned short*)(VhB + (long)row * (S_LEN * 2) +
                                            (kv0 + sub * 64) * 2 + scolb),
                    &vbuf[b][sub][rowbase * 64]);
      }
    }
  };

  short8 qf[4];
#pragma unroll
  for (int d0 = 0; d0 < 4; ++d0)
    qf[d0] = *reinterpret_cast<const short8*>(&Qh[(long)(q0 + q) * DK + d0 * 16 + h * 8]);

  // bf16 1.0 splat for the l-sum MFMA A-operand
  union { short s[8]; short8 v; } ones_u;
#pragma unroll
  for (int i = 0; i < 8; ++i) ones_u.s[i] = (short)0x3F80;
  const short8 ones8 = ones_u.v;

  f32x16 cacc0 = {}, cacc1 = {};  // ctx^T: d-blocks [0..31], [32..63] x 32 q
  f32x16 lacc = {};               // every reg = running sum_kv p̂[kv][q]
  float mrun = -1e30f;

  stage(0, 0);
  __syncthreads();

  int cur = 0;
  for (int t = 0; t < S_LEN / 128; ++t) {
    if (t + 1 < S_LEN / 128) stage(cur ^ 1, (t + 1) * 128);  // issue-early prefetch

#pragma unroll
    for (int p = 0; p < 2; ++p) {
      const unsigned short* kb = kbuf[cur][p];
      const unsigned short* vb = vbuf[cur][p];

      // ---- QK^T: two independent S^T tiles (kv 0-31, 32-63 of this sub-tile) ----
      short8 kfA[4], kfB[4];
#pragma unroll
      for (int d0 = 0; d0 < 4; ++d0) {
        kfA[d0] = ldsrd(kb, q, d0 * 32 + h * 16);
        kfB[d0] = ldsrd(kb, 32 + q, d0 * 32 + h * 16);
      }
      __builtin_amdgcn_s_setprio(1);
      f32x16 stA = {}, stB = {};
#pragma unroll
      for (int d0 = 0; d0 < 4; ++d0) {
        stA = __builtin_amdgcn_mfma_f32_32x32x16_bf16(kfA[d0], qf[d0], stA, 0, 0, 0);
        stB = __builtin_amdgcn_mfma_f32_32x32x16_bf16(kfB[d0], qf[d0], stB, 0, 0, 0);
      }
      __builtin_amdgcn_s_setprio(0);
      // lane reg r: q col = q, kv_local = (r&3) + 8*(r>>2) + 4*h  (+32 for tile B)

      // ---- online softmax (defer-max; common path has NO cross-lane op) ----
      float t16[16];
#pragma unroll
      for (int r = 0; r < 16; ++r) t16[r] = fmaxf(stA[r], stB[r]);
#pragma unroll
      for (int r = 0; r < 8; ++r) t16[r] = fmaxf(t16[r], t16[r + 8]);
#pragma unroll
      for (int r = 0; r < 4; ++r) t16[r] = fmaxf(t16[r], t16[r + 4]);
      const float pml = fmaxf(fmaxf(t16[0], t16[1]), fmaxf(t16[2], t16[3]));

      if (__any(pml > mrun + 8.0f)) {  // rare; shfl only inside the branch
        const float pm = fmaxf(pml, __shfl_xor(pml, 32));
        const float mnew = fmaxf(mrun, pm);
        const float alpha = __builtin_amdgcn_exp2f(mrun - mnew);
        cacc0 *= alpha;
        cacc1 *= alpha;
        lacc *= alpha;
        mrun = mnew;  // stays pair-uniform: pm is pair-reduced
      }

#pragma unroll
      for (int r = 0; r < 16; ++r) {
        stA[r] = __builtin_amdgcn_exp2f(stA[r] - mrun);
        stB[r] = __builtin_amdgcn_exp2f(stB[r] - mrun);
      }

      // ---- pack P -> bf16 pairs, per tile ----
      unsigned pAA[4], pAB[4], pBA[4], pBB[4];
#pragma unroll
      for (int rq = 0; rq < 4; ++rq) {
        asm("v_cvt_pk_bf16_f32 %0, %1, %2" : "=v"(pAA[rq]) : "v"(stA[4 * rq]), "v"(stA[4 * rq + 1]));
        asm("v_cvt_pk_bf16_f32 %0, %1, %2" : "=v"(pAB[rq]) : "v"(stA[4 * rq + 2]), "v"(stA[4 * rq + 3]));
        asm("v_cvt_pk_bf16_f32 %0, %1, %2" : "=v"(pBA[rq]) : "v"(stB[4 * rq]), "v"(stB[4 * rq + 1]));
        asm("v_cvt_pk_bf16_f32 %0, %1, %2" : "=v"(pBB[rq]) : "v"(stB[4 * rq + 2]), "v"(stB[4 * rq + 3]));
      }

      // ---- PV: batch shuffles, batch V-reads, then MFMA cluster (+ lacc row-sum) ----
      unsigned rA[4], rB[4];
#pragma unroll
      for (int s = 0; s < 4; ++s) {
        const unsigned a0 = (s < 2 ? pAA : pBA)[2 * (s & 1)];
        const unsigned a1 = (s < 2 ? pAA : pBA)[2 * (s & 1) + 1];
        const unsigned b0 = (s < 2 ? pAB : pBB)[2 * (s & 1)];
        const unsigned b1 = (s < 2 ? pAB : pBB)[2 * (s & 1) + 1];
        rA[s] = (unsigned)__shfl_xor((int)(h ? a0 : a1), 32);
        rB[s] = (unsigned)__shfl_xor((int)(h ? b0 : b1), 32);
      }
      short8 vf0[4], vf1[4];
#pragma unroll
      for (int s = 0; s < 4; ++s) {
        vf0[s] = ldsrd(vb, q, s * 32 + h * 16);
        vf1[s] = ldsrd(vb, 32 + q, s * 32 + h * 16);
      }
      __builtin_amdgcn_s_setprio(1);
#pragma unroll
      for (int s = 0; s < 4; ++s) {
        const unsigned a0 = (s < 2 ? pAA : pBA)[2 * (s & 1)];
        const unsigned a1 = (s < 2 ? pAA : pBA)[2 * (s & 1) + 1];
        const unsigned b0 = (s < 2 ? pAB : pBB)[2 * (s & 1)];
        const unsigned b1 = (s < 2 ? pAB : pBB)[2 * (s & 1) + 1];
        union { unsigned w[4]; short8 v; } pf;
        pf.w[0] = h ? rA[s] : a0;
        pf.w[1] = h ? rB[s] : b0;
        pf.w[2] = h ? a1 : rA[s];
        pf.w[3] = h ? b1 : rB[s];
        cacc0 = __builtin_amdgcn_mfma_f32_32x32x16_bf16(vf0[s], pf.v, cacc0, 0, 0, 0);
        cacc1 = __builtin_amdgcn_mfma_f32_32x32x16_bf16(vf1[s], pf.v, cacc1, 0, 0, 0);
        lacc = __builtin_amdgcn_mfma_f32_32x32x16_bf16(ones8, pf.v, lacc, 0, 0, 0);
      }
      __builtin_amdgcn_s_setprio(0);
    }

    __syncthreads();  // drains stage loads; protects both buffers
    cur ^= 1;
  }

  // ---- epilogue: l from ones-MFMA (all regs equal, both halves equal) ----
  const float inv = 1.0f / lacc[0];
  const int b_ = hd >> 4, h_ = hd & 15;
  const long row = ((long)b_ * S_LEN + q0 + q) * DM + h_ * DK;
#pragma unroll
  for (int rq = 0; rq < 4; ++rq) {
    ushort4 w0, w1;
    w0.x = bf_round(cacc0[4 * rq + 0] * inv);
    w0.y = bf_round(cacc0[4 * rq + 1] * inv);
    w0.z = bf_round(cacc0[4 * rq + 2] * inv);
    w0.w = bf_round(cacc0[4 * rq + 3] * inv);
    w1.x = bf_round(cacc1[4 * rq + 0] * inv);
    w1.y = bf_round(cacc1[4 * rq + 1] * inv);
    w1.z = bf_round(cacc1[4 * rq + 2] * inv);
    w1.w = bf_round(cacc1[4 * rq + 3] * inv);
    *reinterpret_cast<ushort4*>(&ctx[row + 8 * rq + 4 * h]) = w0;
    *reinterpret_cast<ushort4*>(&ctx[row + 32 + 8 * rq + 4 * h]) = w1;
  }
}

extern "C" void kernel_launch(void* const* d_in, const int* in_sizes, int n_in,
                              void* d_out, int out_size, void* d_ws, size_t ws_size,
                              hipStream_t stream) {
  const float* X  = (const float*)d_in[0];
  const float* Wq = (const float*)d_in[1];
  const float* bq = (const float*)d_in[2];
  const float* Wk = (const float*)d_in[3];
  const float* bk = (const float*)d_in[4];
  const float* Wv = (const float*)d_in[5];
  const float* bv = (const float*)d_in[6];
  const float* Wo = (const float*)d_in[7];
  const float* bo = (const float*)d_in[8];

  char* ws = (char*)d_ws;
  const long MB = 1l << 20;
  unsigned short* Xbf = (unsigned short*)(ws + 0 * MB);   // 16 MB
  unsigned short* Ctx = Xbf;                              // alias: X dead after V GEMM
  unsigned short* Wqb = (unsigned short*)(ws + 16 * MB);  // 2 MB each
  unsigned short* Wkb = (unsigned short*)(ws + 18 * MB);
  unsigned short* Wvb = (unsigned short*)(ws + 20 * MB);
  unsigned short* Wob = (unsigned short*)(ws + 22 * MB);
  unsigned short* Qb  = (unsigned short*)(ws + 24 * MB);  // 16 MB
  unsigned short* Kbf = (unsigned short*)(ws + 40 * MB);  // 16 MB
  unsigned short* Vtb = (unsigned short*)(ws + 56 * MB);  // 16 MB, ends at 72 MB

  CvtArgs ca;
  ca.in[0] = X;  ca.out[0] = Xbf;
  ca.in[1] = Wq; ca.out[1] = Wqb;
  ca.in[2] = Wk; ca.out[2] = Wkb;
  ca.in[3] = Wv; ca.out[3] = Wvb;
  ca.in[4] = Wo; ca.out[4] = Wob;
  cvt_all<<<4096 + 4 * 512, 256, 0, stream>>>(ca);

  QkvArgs qa;
  qa.W[0] = Wqb; qa.bias[0] = bq; qa.out[0] = Qb;
  qa.W[1] = Wkb; qa.bias[1] = bk; qa.out[1] = Kbf;
  qa.W[2] = Wvb; qa.bias[2] = bv; qa.out[2] = Vtb;
  gemm_qkv<<<dim3(M_TOT / 128, DM / 128, 3), 256, 0, stream>>>(Xbf, qa);

  attn_kernel<<<dim3(1024), 256, 0, stream>>>(Qb, Kbf, Vtb, Ctx);

  gemm_out<<<dim3(M_TOT / 128, DM / 128), 256, 0, stream>>>(Ctx, Wob, bo, (float*)d_out);
}